// Round 2
// baseline (604.371 us; speedup 1.0000x reference)
//
#include <hip/hip_runtime.h>

// GCN layer on MI355X (gfx950) — ALL tensors fp32 (per reference dtypes).
// x[100000,512], edge_index[2,3200000] i32, W1[512,16], b1[16], W2[16,2], b2[2]
//   -> out[100000,2] fp32.
//
// Math refactor: s[j] = dinv[j] * (x@W1)[j],  dinv = rsqrt(indeg+1)
//   out_i = ( dinv[i] * ( sum_{edges j->i} s[j] + s[i] ) + b1 ) @ W2 + b2
//
// Projection uses bf16 MFMA with hi/lo split (x=xh+xl, W=wh+wl; keep
// xh*wh + xl*wh + xh*wl) => ~2^-17 relative error, far under the 2% threshold.

constexpr int N_NODES = 100000;
constexpr int N_EDGES = 3200000;
constexpr int IN_CH   = 512;
constexpr int HID     = 16;

typedef __attribute__((ext_vector_type(8))) short short8;   // 8 x bf16 bits
typedef __attribute__((ext_vector_type(4))) float floatx4;
typedef __attribute__((ext_vector_type(2))) float floatx2;

__device__ __forceinline__ short bf16_rne(float f) {
    unsigned u = __float_as_uint(f);
    unsigned r = 0x7fffu + ((u >> 16) & 1u);
    return (short)((u + r) >> 16);
}
__device__ __forceinline__ float bf16_to_f32(short s) {
    return __uint_as_float(((unsigned)(unsigned short)s) << 16);
}

// ---- workspace layout (bytes) ----
// [0        , 400000 )  deg   : int[N_NODES]          (memset 0)
// [400000   , 6800000)  acc   : float[N_NODES*16]     (memset 0)
// [6800000  , 7200000)  dinv  : float[N_NODES]
// [7200000  , 13600000) xws   : float[N_NODES*16]     (s[j] above)

__global__ __launch_bounds__(256) void deg_kernel(const int* __restrict__ col,
                                                  int* __restrict__ deg) {
    int i = blockIdx.x * 256 + threadIdx.x;
    if (i < N_EDGES) atomicAdd(&deg[col[i]], 1);
}

__global__ __launch_bounds__(256) void dinv_kernel(const int* __restrict__ deg,
                                                   float* __restrict__ dinv) {
    int i = blockIdx.x * 256 + threadIdx.x;
    if (i < N_NODES) dinv[i] = rsqrtf((float)(deg[i] + 1));  // +1 self loop => >0
}

// xws[n][h] = dinv[n] * sum_c x[n][c] * W1[c][h] via split-bf16 MFMA.
// One wave per 16-node tile. A: lane(m,quad) reads x[base+m][quad*8 + t*32 ..+7]
// (two float4 global loads, 16B/lane). B: from LDS-transposed split W1.
__global__ __launch_bounds__(256) void xw_kernel(const float* __restrict__ x,
                                                 const float* __restrict__ W1,
                                                 const float* __restrict__ dinv,
                                                 float* __restrict__ xws) {
    __shared__ short w1h[HID * IN_CH];  // [h][c] hi bf16 bits (16 KiB)
    __shared__ short w1l[HID * IN_CH];  // [h][c] lo bf16 bits (16 KiB)
    for (int idx = threadIdx.x; idx < IN_CH * HID; idx += 256) {
        int c = idx >> 4, h = idx & 15;
        float w = W1[idx];
        short hi = bf16_rne(w);
        short lo = bf16_rne(w - bf16_to_f32(hi));
        w1h[h * IN_CH + c] = hi;
        w1l[h * IN_CH + c] = lo;
    }
    __syncthreads();

    const int wave = threadIdx.x >> 6;
    const int lane = threadIdx.x & 63;
    const int quad = lane >> 4;
    const int m    = lane & 15;
    const int base = (blockIdx.x * 4 + wave) * 16;
    if (base >= N_NODES) return;

    int node_a = base + m;
    if (node_a >= N_NODES) node_a = N_NODES - 1;  // clamp; stores masked below
    const floatx4* xr = reinterpret_cast<const floatx4*>(
        x + (long long)node_a * IN_CH + quad * 8);
    const short8* bhp = reinterpret_cast<const short8*>(&w1h[m * IN_CH + quad * 8]);
    const short8* blp = reinterpret_cast<const short8*>(&w1l[m * IN_CH + quad * 8]);

    floatx4 acc = {0.f, 0.f, 0.f, 0.f};
#pragma unroll
    for (int t = 0; t < IN_CH / 32; ++t) {  // 16 K-chunks of 32
        floatx4 a0 = xr[t * 8];             // x fp32, channels quad*8+t*32 .. +3
        floatx4 a1 = xr[t * 8 + 1];         // .. +4..7
        short8 ah, al;
#pragma unroll
        for (int j = 0; j < 4; ++j) {
            float v0 = a0[j], v1 = a1[j];
            short h0 = bf16_rne(v0), h1 = bf16_rne(v1);
            ah[j]     = h0;
            ah[j + 4] = h1;
            al[j]     = bf16_rne(v0 - bf16_to_f32(h0));
            al[j + 4] = bf16_rne(v1 - bf16_to_f32(h1));
        }
        short8 vbh = bhp[t * 4];  // (t*4)*8 shorts = t*32 element stride
        short8 vbl = blp[t * 4];
        acc = __builtin_amdgcn_mfma_f32_16x16x32_bf16(ah, vbh, acc, 0, 0, 0);
        acc = __builtin_amdgcn_mfma_f32_16x16x32_bf16(al, vbh, acc, 0, 0, 0);
        acc = __builtin_amdgcn_mfma_f32_16x16x32_bf16(ah, vbl, acc, 0, 0, 0);
    }

    // C/D layout: col = lane&15, row = quad*4 + reg  [m89-verified]
#pragma unroll
    for (int r = 0; r < 4; ++r) {
        int node = base + quad * 4 + r;
        if (node < N_NODES) xws[node * HID + m] = acc[r] * dinv[node];
    }
}

// One thread per (edge, channel): 16 consecutive lanes = one edge's 64B row.
__global__ __launch_bounds__(256) void scatter_kernel(const int* __restrict__ ei,
                                                      const float* __restrict__ xws,
                                                      float* __restrict__ acc) {
    int t = blockIdx.x * 256 + threadIdx.x;  // grid exactly N_EDGES*16 threads
    int e = t >> 4;
    int h = t & 15;
    int r = ei[e];             // source j
    int c = ei[N_EDGES + e];   // target i
    float v = xws[r * HID + h];
    unsafeAtomicAdd(&acc[c * HID + h], v);  // HW global_atomic_add_f32
}

__global__ __launch_bounds__(256) void final_kernel(const float* __restrict__ acc,
                                                    const float* __restrict__ xws,
                                                    const float* __restrict__ dinv,
                                                    const float* __restrict__ b1,
                                                    const float* __restrict__ W2,
                                                    const float* __restrict__ b2,
                                                    floatx2* __restrict__ out) {
    int i = blockIdx.x * 256 + threadIdx.x;
    if (i >= N_NODES) return;
    float di = dinv[i];
    float o0 = b2[0];
    float o1 = b2[1];
    const floatx4* a4 = reinterpret_cast<const floatx4*>(acc + i * HID);
    const floatx4* x4 = reinterpret_cast<const floatx4*>(xws + i * HID);
#pragma unroll
    for (int j = 0; j < 4; ++j) {
        floatx4 av = a4[j];
        floatx4 xv = x4[j];
#pragma unroll
        for (int k = 0; k < 4; ++k) {
            int h = j * 4 + k;
            float hv = di * (av[k] + xv[k]) + b1[h];
            o0 += hv * W2[h * 2 + 0];
            o1 += hv * W2[h * 2 + 1];
        }
    }
    floatx2 o = {o0, o1};
    out[i] = o;
}

extern "C" void kernel_launch(void* const* d_in, const int* in_sizes, int n_in,
                              void* d_out, int out_size, void* d_ws, size_t ws_size,
                              hipStream_t stream) {
    const float* x  = (const float*)d_in[0];
    const int*   ei = (const int*)d_in[1];
    const float* W1 = (const float*)d_in[2];
    const float* b1 = (const float*)d_in[3];
    const float* W2 = (const float*)d_in[4];
    const float* b2 = (const float*)d_in[5];

    char* ws = (char*)d_ws;
    int*   deg  = (int*)  (ws + 0);
    float* accb = (float*)(ws + 400000);
    float* dinv = (float*)(ws + 6800000);
    float* xws  = (float*)(ws + 7200000);

    hipMemsetAsync(d_ws, 0, 6800000, stream);  // zero deg + acc

    deg_kernel<<<(N_EDGES + 255) / 256, 256, 0, stream>>>(ei + N_EDGES, deg);
    dinv_kernel<<<(N_NODES + 255) / 256, 256, 0, stream>>>(deg, dinv);
    xw_kernel<<<(N_NODES + 63) / 64, 256, 0, stream>>>(x, W1, dinv, xws);
    scatter_kernel<<<(N_EDGES * 16) / 256, 256, 0, stream>>>(ei, xws, accb);
    final_kernel<<<(N_NODES + 255) / 256, 256, 0, stream>>>(accb, xws, dinv, b1, W2, b2,
                                                            (floatx2*)d_out);
}